// Round 1
// 548.711 us; speedup vs baseline: 2.1354x; 2.1354x over previous
//
#include <hip/hip_runtime.h>
#include <float.h>
#include <stdint.h>

// Problem constants
#define BB   128      // bs*t
#define CCH  256      // z channels
#define EMB_ 256      // embedding dim
#define HW   256      // h*w
#define NPIX 32768    // BB*HW
#define VOC  4096

typedef _Float16 f16x8 __attribute__((ext_vector_type(8)));
typedef float    f32x4 __attribute__((ext_vector_type(4)));

// async global->LDS, 16B per lane, dest = wave-uniform base + lane*16
__device__ __forceinline__ void async16(void* lds, const void* g) {
    __builtin_amdgcn_global_load_lds((const __attribute__((address_space(1))) uint32_t*)g,
                                     (__attribute__((address_space(3))) uint32_t*)lds,
                                     16, 0, 0);
}

// ---------------------------------------------------------------- K0a: c_sq
__global__ __launch_bounds__(256) void k_csq(const float* __restrict__ cb,
                                             float* __restrict__ csq) {
    int v = blockIdx.x * 256 + threadIdx.x;   // grid 16
    const float4* row = (const float4*)(cb + v * EMB_);
    float s = 0.f;
#pragma unroll 8
    for (int q = 0; q < 64; ++q) {
        float4 a = row[q];
        s = fmaf(a.x, a.x, fmaf(a.y, a.y, fmaf(a.z, a.z, fmaf(a.w, a.w, s))));
    }
    csq[v] = s;
}

// ------------------------------------------- K0b: postcode = post_b + W@cb^T
__global__ __launch_bounds__(256) void k_postcode(const float* __restrict__ cb,
                                                  const float* __restrict__ post_w,
                                                  const float* __restrict__ post_b,
                                                  float* __restrict__ postcode) {
    __shared__ float cbs[16][EMB_];           // 16 codebook rows, 16 KB
    int v0 = blockIdx.x * 16;                 // grid 256
    int c  = threadIdx.x;
#pragma unroll
    for (int r = 0; r < 16; ++r)
        cbs[r][c] = cb[(v0 + r) * EMB_ + c];  // coalesced
    __syncthreads();

    float acc[16];
    float bias = post_b[c];
#pragma unroll
    for (int r = 0; r < 16; ++r) acc[r] = bias;

    const float4* w4p = (const float4*)(post_w + c * EMB_);
    for (int e4 = 0; e4 < 64; ++e4) {
        float4 w4 = w4p[e4];
#pragma unroll
        for (int r = 0; r < 16; ++r) {
            float4 c4 = *(const float4*)&cbs[r][e4 * 4];
            acc[r] = fmaf(w4.x, c4.x, fmaf(w4.y, c4.y,
                     fmaf(w4.z, c4.z, fmaf(w4.w, c4.w, acc[r]))));
        }
    }
#pragma unroll
    for (int r = 0; r < 16; ++r)
        postcode[(v0 + r) * CCH + c] = acc[r];  // coalesced
}

// ---------------------------------------------------- K1: pre-conv -> z_out
__global__ __launch_bounds__(256) void k_preconv(const float* __restrict__ x,
                                                 const float* __restrict__ pre_w,
                                                 const float* __restrict__ pre_b,
                                                 float* __restrict__ zout) {
    __shared__ float xsT[16][260];            // [p][c], +4 pad kills conflicts
    int b   = blockIdx.x >> 4;                // grid 2048
    int hw0 = (blockIdx.x & 15) * 16;
    int tid = threadIdx.x;
    int cg = tid >> 4, p = tid & 15;
#pragma unroll
    for (int it = 0; it < 16; ++it) {
        int c = it * 16 + cg;
        xsT[p][c] = 2.f * x[b * (CCH * HW) + c * HW + hw0 + p] - 1.f;
    }
    __syncthreads();

    int e = tid;
    float acc[16];
    float bias = pre_b[e];
#pragma unroll
    for (int q = 0; q < 16; ++q) acc[q] = bias;

    const float4* w4p = (const float4*)(pre_w + e * CCH);
    for (int c4 = 0; c4 < 64; ++c4) {
        float4 w4 = w4p[c4];
#pragma unroll
        for (int q = 0; q < 16; ++q) {
            float4 xv = *(const float4*)&xsT[q][c4 * 4];
            acc[q] = fmaf(w4.x, xv.x, fmaf(w4.y, xv.y,
                     fmaf(w4.z, xv.z, fmaf(w4.w, xv.w, acc[q]))));
        }
    }
    float* zo = zout + b * (EMB_ * HW) + e * HW + hw0;
#pragma unroll
    for (int q = 0; q < 4; ++q) {
        float4 s;
        s.x = acc[q * 4 + 0]; s.y = acc[q * 4 + 1];
        s.z = acc[q * 4 + 2]; s.w = acc[q * 4 + 3];
        *(float4*)&zo[q * 4] = s;
    }
}

// ---------------------------------------- K1b: split z into fp16 (hi|lo) pack
// A3 layout (fragment-blocked, K=512 = [zh 0..255 | zl 0..255]):
//   A3[pixg(2048)][kc8(64)][row16][e8], value = fp16 part of z*2^8.
// Exactly MFMA A-fragment order: lane reads row=l&15, k-chunk=(l>>4)*8.
__global__ __launch_bounds__(256) void k_prep_z(const float* __restrict__ z,
                                                _Float16* __restrict__ A3) {
    __shared__ float zs[256][17];             // [e][p], pad kills conflicts
    int pixg = blockIdx.x;                    // grid 2048 (16 pixels each)
    int b = pixg >> 4, hw0 = (pixg & 15) << 4;
    int t = threadIdx.x;
    int p = t & 15, eb = (t >> 4) << 4;
    const float* zp = z + b * (EMB_ * HW) + hw0 + p;
#pragma unroll
    for (int j = 0; j < 16; ++j)
        zs[eb + j][p] = zp[(eb + j) * HW];    // 64B-coalesced per 16-lane group
    __syncthreads();
    // 1024 chunks of [row][8 elems]; thread handles 4
#pragma unroll
    for (int it = 0; it < 4; ++it) {
        int c = it * 256 + t;
        int kc8 = c >> 4, row = c & 15;
        int lo = kc8 >> 5;                    // 0: hi part, 1: lo part
        int kh = kc8 & 31;
        f16x8 outv;
#pragma unroll
        for (int j = 0; j < 8; ++j) {
            float v = zs[kh * 8 + j][row] * 256.0f;     // exact 2^8 scale
            _Float16 h = (_Float16)v;                   // RN
            if (lo) h = (_Float16)(v - (float)h);       // exact residual, RN
            outv[j] = h;
        }
        *(f16x8*)(A3 + ((pixg * 64 + kc8) * 128 + row * 8)) = outv;
    }
}

// ---------------------------------------- K0c: split codebook into fp16 pack
// B3[vg(256)][kc8(64)][row16][e8], value = fp16 part of c*2^16.
__global__ __launch_bounds__(256) void k_prep_c(const float* __restrict__ cb,
                                                _Float16* __restrict__ B3) {
    __shared__ float cs[256][17];             // [e][vrow]
    int vg = blockIdx.x;                      // grid 256 (16 codes each)
    int t = threadIdx.x;
    int vr = t >> 4, e0 = (t & 15) << 4;
    const float* cp = cb + (vg * 16 + vr) * EMB_ + e0;
#pragma unroll
    for (int j = 0; j < 16; ++j)
        cs[e0 + j][vr] = cp[j];
    __syncthreads();
#pragma unroll
    for (int it = 0; it < 4; ++it) {
        int c = it * 256 + t;
        int kc8 = c >> 4, row = c & 15;
        int lo = kc8 >> 5;
        int kh = kc8 & 31;
        f16x8 outv;
#pragma unroll
        for (int j = 0; j < 8; ++j) {
            float v = cs[kh * 8 + j][row] * 65536.0f;   // exact 2^16 scale
            _Float16 h = (_Float16)v;
            if (lo) h = (_Float16)(v - (float)h);
            outv[j] = h;
        }
        *(f16x8*)(B3 + ((vg * 64 + kc8) * 128 + row * 8)) = outv;
    }
}

// --------------------------------- K2: MFMA distance GEMM + fused argmin
// dot*2^24 = zh*ch + zh*cl + zl*ch  (3 K=256 terms = concat K=768 f16 GEMM).
// dist = fl( fl(zsq + csq[v]) - acc*2^-23 ), argmin first-index — identical
// rounding structure to the previous passing kernel; only the dot changes,
// by ~3e-10 rms (same decade as fp32 reorder noise).
// Block: 128 pixels x 256 codes/tile, 16 code-tiles, 8 waves (2M x 4N),
// each wave 64x64 = 4x4 mfma_f32_16x16x32_f16 fragments. Double-buffered
// linear LDS staged with global_load_lds dwordx4 (fragment-blocked layout
// in global => conflict-free ds_read_b128, no swizzle needed).
__global__ __launch_bounds__(512) void k_dist(const float* __restrict__ zout,
                                              const _Float16* __restrict__ A3,
                                              const _Float16* __restrict__ B3,
                                              const float* __restrict__ csq,
                                              float* __restrict__ tok_f) {
    __shared__ __align__(16) _Float16 Ab[2][8192];    // [g8][u8][16][8] 16KB x2
    __shared__ __align__(16) _Float16 Bb[2][16384];   // [ng16][u8][16][8] 32KB x2
    __shared__ float csq_s[VOC];                      // 16 KB
    __shared__ float zsq_s[128];
    __shared__ float red_b[8][64];
    __shared__ int   red_i[8][64];

    const int tid = threadIdx.x;
    const int l   = tid & 63;
    const int w   = tid >> 6;
    const int l15 = l & 15, l4 = l >> 4;
    const int wr  = w >> 2, wc = w & 3;
    const int bM  = blockIdx.x;               // grid 256, 128 pixels each

    // csq -> LDS
#pragma unroll
    for (int i = 0; i < 8; ++i) csq_s[i * 512 + tid] = csq[i * 512 + tid];

    // issue stage of chunk (vt=0, kc=0, term hh) into buffer 0
    {
#pragma unroll
        for (int i = 0; i < 2; ++i) {
            int q = w * 8 + i * 4 + l4;
            const _Float16* g = A3 + ((bM * 8 + (q >> 3)) * 64 + (q & 7)) * 128 + l15 * 8;
            async16(&Ab[0][(w * 8 + i * 4) * 128], g);
        }
#pragma unroll
        for (int i = 0; i < 4; ++i) {
            int q = w * 16 + i * 4 + l4;
            const _Float16* g = B3 + ((q >> 3) * 64 + (q & 7)) * 128 + l15 * 8;
            async16(&Bb[0][(w * 16 + i * 4) * 128], g);
        }
    }

    // zsq: serial fmaf chain over e (order identical to passing kernel)
    if (tid < 128) {
        const float* zp = zout + (bM >> 1) * (EMB_ * HW) + ((bM & 1) << 7) + tid;
        float s = 0.f;
        for (int k = 0; k < 256; ++k) { float zv = zp[k * HW]; s = fmaf(zv, zv, s); }
        zsq_s[tid] = s;
    }
    __syncthreads();

    float zq[16];
#pragma unroll
    for (int s = 0; s < 4; ++s)
#pragma unroll
        for (int r = 0; r < 4; ++r)
            zq[s * 4 + r] = zsq_s[(wr * 4 + s) * 16 + l4 * 4 + r];

    float best[16]; int bidx[16];
#pragma unroll
    for (int i = 0; i < 16; ++i) { best[i] = FLT_MAX; bidx[i] = 0; }

    const f32x4 zero4 = {0.f, 0.f, 0.f, 0.f};
    int buf = 0;
    for (int vt = 0; vt < 16; ++vt) {
        f32x4 acc[4][4];
#pragma unroll
        for (int s = 0; s < 4; ++s)
#pragma unroll
            for (int n = 0; n < 4; ++n) acc[s][n] = zero4;

        for (int kc = 0; kc < 12; ++kc) {
            // ---- issue next chunk into buf^1 (in flight across this compute)
            int nvt = vt, nkc = kc + 1;
            if (nkc == 12) { nkc = 0; ++nvt; }
            if (nvt < 16) {
                int tau = (nkc >= 8) ? 2 : ((nkc >= 4) ? 1 : 0); // hh, hl, lh
                int kc4 = nkc - tau * 4;
                int kA = ((tau == 2) ? 32 : 0) + kc4 * 8;        // zl for lh
                int kB = ((tau == 1) ? 32 : 0) + kc4 * 8;        // cl for hl
#pragma unroll
                for (int i = 0; i < 2; ++i) {
                    int q = w * 8 + i * 4 + l4;
                    const _Float16* g = A3 + ((bM * 8 + (q >> 3)) * 64 + kA + (q & 7)) * 128 + l15 * 8;
                    async16(&Ab[buf ^ 1][(w * 8 + i * 4) * 128], g);
                }
#pragma unroll
                for (int i = 0; i < 4; ++i) {
                    int q = w * 16 + i * 4 + l4;
                    const _Float16* g = B3 + ((nvt * 16 + (q >> 3)) * 64 + kB + (q & 7)) * 128 + l15 * 8;
                    async16(&Bb[buf ^ 1][(w * 16 + i * 4) * 128], g);
                }
            }
            // ---- compute current chunk (Kc = 64 = 2 MFMA k-steps)
#pragma unroll
            for (int t = 0; t < 2; ++t) {
                f16x8 af[4], bf[4];
#pragma unroll
                for (int s = 0; s < 4; ++s)
                    af[s] = *(const f16x8*)&Ab[buf][((wr * 4 + s) * 8 + t * 4 + l4) * 128 + l15 * 8];
#pragma unroll
                for (int n = 0; n < 4; ++n)
                    bf[n] = *(const f16x8*)&Bb[buf][((wc * 4 + n) * 8 + t * 4 + l4) * 128 + l15 * 8];
#pragma unroll
                for (int s = 0; s < 4; ++s)
#pragma unroll
                    for (int n = 0; n < 4; ++n)
                        acc[s][n] = __builtin_amdgcn_mfma_f32_16x16x32_f16(af[s], bf[n], acc[s][n], 0, 0, 0);
            }
            __syncthreads();
            buf ^= 1;
        }
        // ---- fold tile into running argmin (codes ascending within lane)
#pragma unroll
        for (int n = 0; n < 4; ++n) {
            int code = vt * 256 + (wc * 4 + n) * 16 + l15;
            float cs = csq_s[code];
#pragma unroll
            for (int s = 0; s < 4; ++s)
#pragma unroll
                for (int r = 0; r < 4; ++r) {
                    float dd = (zq[s * 4 + r] + cs) - acc[s][n][r] * 0x1p-23f;
                    int pi = s * 4 + r;
                    if (dd < best[pi]) { best[pi] = dd; bidx[pi] = code; }
                }
        }
    }

    // in-wave lexicographic reduce over the 16 code columns
#pragma unroll
    for (int off = 8; off >= 1; off >>= 1) {
#pragma unroll
        for (int i = 0; i < 16; ++i) {
            float ob = __shfl_xor(best[i], off, 64);
            int   oi = __shfl_xor(bidx[i], off, 64);
            if (ob < best[i] || (ob == best[i] && oi < bidx[i])) { best[i] = ob; bidx[i] = oi; }
        }
    }
    if (l15 == 0) {
#pragma unroll
        for (int s = 0; s < 4; ++s)
#pragma unroll
            for (int r = 0; r < 4; ++r) {
                int lp = s * 16 + l4 * 4 + r;             // wave-local pixel
                red_b[w][lp] = best[s * 4 + r];
                red_i[w][lp] = bidx[s * 4 + r];
            }
    }
    __syncthreads();
    // cross-wave (4 code-quarters) lexicographic combine + store tokens
    if (tid < 128) {
        int wrg = tid >> 6, lp = tid & 63;
        float bb = red_b[wrg * 4][lp]; int bi = red_i[wrg * 4][lp];
#pragma unroll
        for (int c = 1; c < 4; ++c) {
            float ob = red_b[wrg * 4 + c][lp]; int oi = red_i[wrg * 4 + c][lp];
            if (ob < bb || (ob == bb && oi < bi)) { bb = ob; bi = oi; }
        }
        tok_f[bM * 128 + wrg * 64 + lp] = (float)bi;
    }
}

// ------------------------- K3: gather zq_out = cb[t], recon = postcode[t]
__global__ __launch_bounds__(256) void k_gather(const float* __restrict__ tok_f,
                                                const float* __restrict__ cb,
                                                const float* __restrict__ postcode,
                                                float* __restrict__ zq_out,
                                                float* __restrict__ recon) {
    int b  = blockIdx.x >> 3;                 // grid 1024
    int e0 = (blockIdx.x & 7) * 32;
    int hw = threadIdx.x;
    int t  = (int)tok_f[b * HW + hw];
    const float* cbr = cb       + t * EMB_;
    const float* pcr = postcode + t * CCH;
    float* zq = zq_out + b * (EMB_ * HW) + hw;
    float* rc = recon  + b * (CCH * HW) + hw;
#pragma unroll
    for (int j = 0; j < 32; ++j) {
        int e = e0 + j;
        zq[e * HW] = cbr[e];                  // stores coalesced across hw
        rc[e * HW] = pcr[e];
    }
}

extern "C" void kernel_launch(void* const* d_in, const int* in_sizes, int n_in,
                              void* d_out, int out_size, void* d_ws, size_t ws_size,
                              hipStream_t stream) {
    const float* x      = (const float*)d_in[0];
    const float* cb     = (const float*)d_in[1];
    const float* pre_w  = (const float*)d_in[2];
    const float* pre_b  = (const float*)d_in[3];
    const float* post_w = (const float*)d_in[4];
    const float* post_b = (const float*)d_in[5];

    float* out    = (float*)d_out;
    float* z_out  = out;                       //  8388608 elems
    float* zq_out = out + 8388608;             //  8388608
    float* recon  = out + 16777216;            //  8388608
    float* tok_f  = out + 25165824;            //    32768

    // Scratch-in-output: A3 (33.55 MB) lives in zq_out, B3 (4 MB) in recon.
    // Both are fully consumed by k_dist and overwritten by k_gather afterward,
    // so ws usage is identical to the previous passing kernel.
    _Float16* A3 = (_Float16*)zq_out;          // [2048][64][16][8] fp16
    _Float16* B3 = (_Float16*)recon;           // [256][64][16][8]  fp16

    float* csq      = (float*)d_ws;            // 4096 floats
    float* postcode = csq + VOC;               // 4096*256 floats (4 MB)

    k_csq     <<<  16, 256, 0, stream>>>(cb, csq);
    k_postcode<<< 256, 256, 0, stream>>>(cb, post_w, post_b, postcode);
    k_prep_c  <<< 256, 256, 0, stream>>>(cb, B3);
    k_preconv <<<2048, 256, 0, stream>>>(x, pre_w, pre_b, z_out);
    k_prep_z  <<<2048, 256, 0, stream>>>(z_out, A3);
    k_dist    <<< 256, 512, 0, stream>>>(z_out, A3, B3, csq, tok_f);
    k_gather  <<<1024, 256, 0, stream>>>(tok_f, cb, postcode, zq_out, recon);
}